// Round 1
// baseline (1754.541 us; speedup 1.0000x reference)
//
#include <hip/hip_runtime.h>
#include <hip/hip_bf16.h>

#define C       228
#define TT      1024
#define NPOS    2048      // B*T
#define LANESN  4
#define HD      57
#define VOC     50257
#define KPAD    256
#define HID     912
#define NLAYER  4

typedef __bf16 bf16x8 __attribute__((ext_vector_type(8)));
typedef float  f32x4  __attribute__((ext_vector_type(4)));

__device__ __forceinline__ float rdl(float v, int lane) {
    return __int_as_float(__builtin_amdgcn_readlane(__float_as_int(v), lane));
}

// ---------------- weight transpose (generic) ----------------
__global__ void transpose_k(const float* __restrict__ src, float* __restrict__ dst,
                            int R, int Cc, int dstStride, int dstColOff,
                            int srcLayerStride, int dstLayerStride) {
    int layer = blockIdx.y;
    src += (size_t)layer * srcLayerStride;
    dst += (size_t)layer * dstLayerStride;
    int i = blockIdx.x * 256 + threadIdx.x;
    if (i < R * Cc) {
        int r = i / Cc, c = i - r * Cc;
        dst[(size_t)c * dstStride + dstColOff + r] = src[i];
    }
}

// ---------------- embedding ----------------
__global__ void embed_k(const int* __restrict__ idx, const float* __restrict__ wte,
                        float* __restrict__ x) {
    int i = blockIdx.x * 256 + threadIdx.x;   // NPOS*C total
    int n = i / C, c = i - n * C;
    x[i] = wte[(size_t)idx[n] * C + c];
}

// ---------------- LN + dual matmul (qin = h@w_up^T, v = h@w_v^T) ----------------
// 512 threads. Wave wv handles LN of position wv. GEMM: thread = col, readlane h.
__global__ __launch_bounds__(512) void lnuv_k(const float* __restrict__ x, const float* __restrict__ g,
                                              const float* __restrict__ wuvT,
                                              float* __restrict__ qout, float* __restrict__ vout) {
    __shared__ __align__(16) float hsh[8][256];
    int tid = threadIdx.x, nb = blockIdx.x * 8;
    int wv = tid >> 6, ln = tid & 63;
    const float* xr = x + (size_t)(nb + wv) * C;
    float vals[4]; float s = 0.f, ss = 0.f;
#pragma unroll
    for (int j = 0; j < 4; ++j) {
        int c = ln + 64 * j;
        float vv = (c < C) ? xr[c] : 0.f;
        vals[j] = vv; s += vv; ss += vv * vv;
    }
#pragma unroll
    for (int o = 32; o > 0; o >>= 1) { s += __shfl_xor(s, o, 64); ss += __shfl_xor(ss, o, 64); }
    float mean = s * (1.f / C);
    float rstd = rsqrtf(ss * (1.f / C) - mean * mean + 1e-5f);
#pragma unroll
    for (int j = 0; j < 4; ++j) {
        int c = ln + 64 * j;
        hsh[wv][c] = (c < C) ? (vals[j] - mean) * rstd * g[c] : 0.f;
    }
    __syncthreads();
    f32x4 hv[8];
#pragma unroll
    for (int p = 0; p < 8; ++p) hv[p] = *(const f32x4*)&hsh[p][4 * ln];
    int col  = tid;
    int colc = (col < 2 * C) ? col : 0;
    float acc[8] = {0,0,0,0,0,0,0,0};
    const float* wcol = wuvT + colc;
    for (int c4 = 0; c4 < 57; ++c4) {
        float w0 = wcol[(size_t)(c4 * 4 + 0) * (2 * C)];
        float w1 = wcol[(size_t)(c4 * 4 + 1) * (2 * C)];
        float w2 = wcol[(size_t)(c4 * 4 + 2) * (2 * C)];
        float w3 = wcol[(size_t)(c4 * 4 + 3) * (2 * C)];
#pragma unroll
        for (int p = 0; p < 8; ++p) {
            acc[p] = fmaf(rdl(hv[p].x, c4), w0, acc[p]);
            acc[p] = fmaf(rdl(hv[p].y, c4), w1, acc[p]);
            acc[p] = fmaf(rdl(hv[p].z, c4), w2, acc[p]);
            acc[p] = fmaf(rdl(hv[p].w, c4), w3, acc[p]);
        }
    }
    if (col < C) {
#pragma unroll
        for (int p = 0; p < 8; ++p) qout[(size_t)(nb + p) * C + col] = acc[p];
    } else if (col < 2 * C) {
#pragma unroll
        for (int p = 0; p < 8; ++p) vout[(size_t)(nb + p) * C + col - C] = acc[p];
    }
}

// ---------------- fused scan step (512 threads) ----------------
__global__ __launch_bounds__(512) void scan_k(const float* __restrict__ src, float* __restrict__ dst,
                                              const float* __restrict__ wscan,
                                              const float* __restrict__ ident, int off) {
    __shared__ __align__(16) float lsh[8][232];
    __shared__ __align__(16) float rsh[8][232];
    __shared__ __align__(16) float ush[8][256];
    __shared__ __align__(16) float vmsh[8][232];
    __shared__ __align__(16) float zsh[8][232];
    int tid = threadIdx.x;
    int nb  = blockIdx.x * 8;
    int wv = tid >> 6, ln = tid & 63;
    // Phase A: load left/right, u = l + r
    for (int i = tid; i < 8 * C; i += 512) {
        int p = i / C, c = i - p * C;
        int n = nb + p, t = n & (TT - 1);
        float r = src[(size_t)nb * C + i];
        float l = (t >= off) ? src[(size_t)(n - off) * C + c] : ident[c];
        lsh[p][c] = l; rsh[p][c] = r; ush[p][c] = l + r;
    }
    if (tid < 256) { int p = tid >> 5, c = 228 + (tid & 31); if (c < 256) ush[p][c] = 0.f; }
    __syncthreads();
    // Phase B: vmix = u @ wscan, position-split (waves 0-3 -> pos 0-3, waves 4-7 -> pos 4-7)
    {
        int half = (tid >= 256) ? 4 : 0;
        int col  = tid & 255;
        int colc = (col < C) ? col : 0;
        f32x4 hv0 = *(const f32x4*)&ush[half + 0][4 * ln];
        f32x4 hv1 = *(const f32x4*)&ush[half + 1][4 * ln];
        f32x4 hv2 = *(const f32x4*)&ush[half + 2][4 * ln];
        f32x4 hv3 = *(const f32x4*)&ush[half + 3][4 * ln];
        float a0 = 0.f, a1 = 0.f, a2 = 0.f, a3 = 0.f;
        const float* wcol = wscan + colc;
        for (int c4 = 0; c4 < 57; ++c4) {
            float w0 = wcol[(size_t)(c4 * 4 + 0) * C];
            float w1 = wcol[(size_t)(c4 * 4 + 1) * C];
            float w2 = wcol[(size_t)(c4 * 4 + 2) * C];
            float w3 = wcol[(size_t)(c4 * 4 + 3) * C];
            a0 = fmaf(rdl(hv0.x, c4), w0, a0); a0 = fmaf(rdl(hv0.y, c4), w1, a0);
            a0 = fmaf(rdl(hv0.z, c4), w2, a0); a0 = fmaf(rdl(hv0.w, c4), w3, a0);
            a1 = fmaf(rdl(hv1.x, c4), w0, a1); a1 = fmaf(rdl(hv1.y, c4), w1, a1);
            a1 = fmaf(rdl(hv1.z, c4), w2, a1); a1 = fmaf(rdl(hv1.w, c4), w3, a1);
            a2 = fmaf(rdl(hv2.x, c4), w0, a2); a2 = fmaf(rdl(hv2.y, c4), w1, a2);
            a2 = fmaf(rdl(hv2.z, c4), w2, a2); a2 = fmaf(rdl(hv2.w, c4), w3, a2);
            a3 = fmaf(rdl(hv3.x, c4), w0, a3); a3 = fmaf(rdl(hv3.y, c4), w1, a3);
            a3 = fmaf(rdl(hv3.z, c4), w2, a3); a3 = fmaf(rdl(hv3.w, c4), w3, a3);
        }
        if (col < C) {
            vmsh[half + 0][col] = a0; vmsh[half + 1][col] = a1;
            vmsh[half + 2][col] = a2; vmsh[half + 3][col] = a3;
        }
    }
    __syncthreads();
    // Phase C: wave-local attention for position wv (no further block barriers)
    float att = 0.f;
    {
        int l = (ln >> 2) & 3, m = ln & 3;
        float sc = 0.f;
        if (ln < 16) {
            const float* qv = &lsh[wv][l * HD];
            const float* kv = &rsh[wv][m * HD];
            for (int d = 0; d < HD; ++d) sc = fmaf(qv[d], kv[d], sc);
            sc *= 0.13245323570650439f;  // 1/sqrt(57)
        }
        float mx = fmaxf(sc, __shfl_xor(sc, 1, 4));
        mx = fmaxf(mx, __shfl_xor(mx, 2, 4));
        float e = expf(sc - mx);
        float se = e + __shfl_xor(e, 1, 4);
        se += __shfl_xor(se, 2, 4);
        att = e / se;    // lane (4l+m) holds att[l][m]; lanes>=16 hold junk (never read)
    }
    float zreg[4];
    int lidx[4];
#pragma unroll
    for (int j = 0; j < 4; ++j) {
        int c = ln + 64 * j;
        zreg[j] = 0.f; lidx[j] = 0;
        if (c < C) {
            int l = (c >= 171) + (c >= 114) + (c >= 57);
            int d = c - 57 * l;
            float b0 = __shfl(att, 4 * l + 0, 64);
            float b1 = __shfl(att, 4 * l + 1, 64);
            float b2 = __shfl(att, 4 * l + 2, 64);
            float b3 = __shfl(att, 4 * l + 3, 64);
            float z = b0 * vmsh[wv][d] + b1 * vmsh[wv][HD + d]
                    + b2 * vmsh[wv][2 * HD + d] + b3 * vmsh[wv][3 * HD + d];
            zsh[wv][c] = z; zreg[j] = z; lidx[j] = l;
        }
    }
    // rms per lane-group: same-wave LDS write->read (in-order LDS pipe)
    float rs = 0.f;
    if (ln < 4) {
        float zz = 0.f;
        const float* zr = &zsh[wv][ln * HD];
        for (int d = 0; d < HD; ++d) zz = fmaf(zr[d], zr[d], zz);
        rs = rsqrtf(zz * (1.f / HD) + 1e-6f) / (float)(1 + ln);
    }
#pragma unroll
    for (int j = 0; j < 4; ++j) {
        int c = ln + 64 * j;
        if (c < C) {
            float rsl = __shfl(rs, lidx[j], 64);
            dst[(size_t)(nb + wv) * C + c] = lsh[wv][c] + zreg[j] * rsl;
        }
    }
}

// ---------------- cproj: x += (q*v) @ w_cproj^T (512 thr, pos-split) ----------------
__global__ __launch_bounds__(512) void cproj_k(const float* __restrict__ q, const float* __restrict__ v,
                                               const float* __restrict__ wcT, float* __restrict__ x) {
    __shared__ __align__(16) float psh[8][256];
    int tid = threadIdx.x, nb = blockIdx.x * 8;
    int ln = tid & 63;
    for (int i = tid; i < 8 * 256; i += 512) {
        int p = i >> 8, c = i & 255;
        psh[p][c] = (c < C) ? q[(size_t)(nb + p) * C + c] * v[(size_t)(nb + p) * C + c] : 0.f;
    }
    __syncthreads();
    int half = (tid >= 256) ? 4 : 0;
    int col  = tid & 255;
    int colc = (col < C) ? col : 0;
    f32x4 hv0 = *(const f32x4*)&psh[half + 0][4 * ln];
    f32x4 hv1 = *(const f32x4*)&psh[half + 1][4 * ln];
    f32x4 hv2 = *(const f32x4*)&psh[half + 2][4 * ln];
    f32x4 hv3 = *(const f32x4*)&psh[half + 3][4 * ln];
    float a0 = 0.f, a1 = 0.f, a2 = 0.f, a3 = 0.f;
    const float* wcol = wcT + colc;
    for (int c4 = 0; c4 < 57; ++c4) {
        float w0 = wcol[(size_t)(c4 * 4 + 0) * C];
        float w1 = wcol[(size_t)(c4 * 4 + 1) * C];
        float w2 = wcol[(size_t)(c4 * 4 + 2) * C];
        float w3 = wcol[(size_t)(c4 * 4 + 3) * C];
        a0 = fmaf(rdl(hv0.x, c4), w0, a0); a0 = fmaf(rdl(hv0.y, c4), w1, a0);
        a0 = fmaf(rdl(hv0.z, c4), w2, a0); a0 = fmaf(rdl(hv0.w, c4), w3, a0);
        a1 = fmaf(rdl(hv1.x, c4), w0, a1); a1 = fmaf(rdl(hv1.y, c4), w1, a1);
        a1 = fmaf(rdl(hv1.z, c4), w2, a1); a1 = fmaf(rdl(hv1.w, c4), w3, a1);
        a2 = fmaf(rdl(hv2.x, c4), w0, a2); a2 = fmaf(rdl(hv2.y, c4), w1, a2);
        a2 = fmaf(rdl(hv2.z, c4), w2, a2); a2 = fmaf(rdl(hv2.w, c4), w3, a2);
        a3 = fmaf(rdl(hv3.x, c4), w0, a3); a3 = fmaf(rdl(hv3.y, c4), w1, a3);
        a3 = fmaf(rdl(hv3.z, c4), w2, a3); a3 = fmaf(rdl(hv3.w, c4), w3, a3);
    }
    if (col < C) {
        x[(size_t)(nb + half + 0) * C + col] += a0;
        x[(size_t)(nb + half + 1) * C + col] += a1;
        x[(size_t)(nb + half + 2) * C + col] += a2;
        x[(size_t)(nb + half + 3) * C + col] += a3;
    }
}

// ---------------- LN2 + fc + gelu (512 thr, 2 cols/thread) ----------------
__global__ __launch_bounds__(512) void lnfc_k(const float* __restrict__ x, const float* __restrict__ g,
                                              const float* __restrict__ wfcT, float* __restrict__ hid) {
    __shared__ __align__(16) float hsh[8][256];
    int tid = threadIdx.x, nb = blockIdx.x * 8;
    int wv = tid >> 6, ln = tid & 63;
    const float* xr = x + (size_t)(nb + wv) * C;
    float vals[4]; float s = 0.f, ss = 0.f;
#pragma unroll
    for (int j = 0; j < 4; ++j) {
        int c = ln + 64 * j;
        float vv = (c < C) ? xr[c] : 0.f;
        vals[j] = vv; s += vv; ss += vv * vv;
    }
#pragma unroll
    for (int o = 32; o > 0; o >>= 1) { s += __shfl_xor(s, o, 64); ss += __shfl_xor(ss, o, 64); }
    float mean = s * (1.f / C);
    float rstd = rsqrtf(ss * (1.f / C) - mean * mean + 1e-5f);
#pragma unroll
    for (int j = 0; j < 4; ++j) {
        int c = ln + 64 * j;
        hsh[wv][c] = (c < C) ? (vals[j] - mean) * rstd * g[c] : 0.f;
    }
    __syncthreads();
    f32x4 hv[8];
#pragma unroll
    for (int p = 0; p < 8; ++p) hv[p] = *(const f32x4*)&hsh[p][4 * ln];
    int c0 = tid;
    int c1 = tid + 512;
    int c1c = (c1 < HID) ? c1 : 0;
    float acc0[8] = {0,0,0,0,0,0,0,0};
    float acc1[8] = {0,0,0,0,0,0,0,0};
    const float* w0p = wfcT + c0;
    const float* w1p = wfcT + c1c;
    for (int c4 = 0; c4 < 57; ++c4) {
        float wa0 = w0p[(size_t)(c4 * 4 + 0) * HID];
        float wa1 = w0p[(size_t)(c4 * 4 + 1) * HID];
        float wa2 = w0p[(size_t)(c4 * 4 + 2) * HID];
        float wa3 = w0p[(size_t)(c4 * 4 + 3) * HID];
        float wb0 = w1p[(size_t)(c4 * 4 + 0) * HID];
        float wb1 = w1p[(size_t)(c4 * 4 + 1) * HID];
        float wb2 = w1p[(size_t)(c4 * 4 + 2) * HID];
        float wb3 = w1p[(size_t)(c4 * 4 + 3) * HID];
#pragma unroll
        for (int p = 0; p < 8; ++p) {
            float h0 = rdl(hv[p].x, c4), h1 = rdl(hv[p].y, c4);
            float h2 = rdl(hv[p].z, c4), h3 = rdl(hv[p].w, c4);
            acc0[p] = fmaf(h0, wa0, acc0[p]); acc0[p] = fmaf(h1, wa1, acc0[p]);
            acc0[p] = fmaf(h2, wa2, acc0[p]); acc0[p] = fmaf(h3, wa3, acc0[p]);
            acc1[p] = fmaf(h0, wb0, acc1[p]); acc1[p] = fmaf(h1, wb1, acc1[p]);
            acc1[p] = fmaf(h2, wb2, acc1[p]); acc1[p] = fmaf(h3, wb3, acc1[p]);
        }
    }
#pragma unroll
    for (int p = 0; p < 8; ++p) {
        float u = acc0[p];
        float th = tanhf(0.7978845608028654f * (u + 0.044715f * u * u * u));
        hid[(size_t)(nb + p) * HID + c0] = 0.5f * u * (1.f + th);
    }
    if (c1 < HID) {
#pragma unroll
        for (int p = 0; p < 8; ++p) {
            float u = acc1[p];
            float th = tanhf(0.7978845608028654f * (u + 0.044715f * u * u * u));
            hid[(size_t)(nb + p) * HID + c1] = 0.5f * u * (1.f + th);
        }
    }
}

// ---------------- proj + residual: x += hid @ w_proj^T (512 thr, pos-split, k-chunked) ----------------
__global__ __launch_bounds__(512) void proj_k(const float* __restrict__ hid,
                                              const float* __restrict__ wpT, float* __restrict__ x) {
    __shared__ __align__(16) float hsh[8][944];
    int tid = threadIdx.x, nb = blockIdx.x * 8;
    int ln = tid & 63;
    for (int i = tid; i < 8 * HID; i += 512) {
        int p = i / HID, c = i - p * HID;
        hsh[p][c] = hid[(size_t)nb * HID + i];
    }
    if (tid < 256) { int p = tid >> 5; hsh[p][912 + (tid & 31)] = 0.f; }
    __syncthreads();
    int half = (tid >= 256) ? 4 : 0;
    int col  = tid & 255;
    int colc = (col < C) ? col : 0;
    float a0 = 0.f, a1 = 0.f, a2 = 0.f, a3 = 0.f;
    const float* wcol = wpT + colc;
    for (int ch = 0; ch < 4; ++ch) {
        f32x4 hv0 = *(const f32x4*)&hsh[half + 0][228 * ch + 4 * ln];
        f32x4 hv1 = *(const f32x4*)&hsh[half + 1][228 * ch + 4 * ln];
        f32x4 hv2 = *(const f32x4*)&hsh[half + 2][228 * ch + 4 * ln];
        f32x4 hv3 = *(const f32x4*)&hsh[half + 3][228 * ch + 4 * ln];
        const float* wch = wcol + (size_t)(228 * ch) * C;
        for (int c4 = 0; c4 < 57; ++c4) {
            float w0 = wch[(size_t)(c4 * 4 + 0) * C];
            float w1 = wch[(size_t)(c4 * 4 + 1) * C];
            float w2 = wch[(size_t)(c4 * 4 + 2) * C];
            float w3 = wch[(size_t)(c4 * 4 + 3) * C];
            a0 = fmaf(rdl(hv0.x, c4), w0, a0); a0 = fmaf(rdl(hv0.y, c4), w1, a0);
            a0 = fmaf(rdl(hv0.z, c4), w2, a0); a0 = fmaf(rdl(hv0.w, c4), w3, a0);
            a1 = fmaf(rdl(hv1.x, c4), w0, a1); a1 = fmaf(rdl(hv1.y, c4), w1, a1);
            a1 = fmaf(rdl(hv1.z, c4), w2, a1); a1 = fmaf(rdl(hv1.w, c4), w3, a1);
            a2 = fmaf(rdl(hv2.x, c4), w0, a2); a2 = fmaf(rdl(hv2.y, c4), w1, a2);
            a2 = fmaf(rdl(hv2.z, c4), w2, a2); a2 = fmaf(rdl(hv2.w, c4), w3, a2);
            a3 = fmaf(rdl(hv3.x, c4), w0, a3); a3 = fmaf(rdl(hv3.y, c4), w1, a3);
            a3 = fmaf(rdl(hv3.z, c4), w2, a3); a3 = fmaf(rdl(hv3.w, c4), w3, a3);
        }
    }
    if (col < C) {
        x[(size_t)(nb + half + 0) * C + col] += a0;
        x[(size_t)(nb + half + 1) * C + col] += a1;
        x[(size_t)(nb + half + 2) * C + col] += a2;
        x[(size_t)(nb + half + 3) * C + col] += a3;
    }
}

// ---------------- bf16 conversions (K padded to 256 with zeros) ----------------
__global__ void convx_k(const float* __restrict__ x, __hip_bfloat16* __restrict__ xbf) {
    int i = blockIdx.x * 256 + threadIdx.x;    // NPOS*KPAD total
    int n = i >> 8, c = i & 255;
    xbf[i] = __float2bfloat16((c < C) ? x[(size_t)n * C + c] : 0.f);
}
__global__ void convw_k(const float* __restrict__ wte, __hip_bfloat16* __restrict__ wbf) {
    size_t i = (size_t)blockIdx.x * 256 + threadIdx.x;   // VOC*KPAD total
    size_t n = i >> 8; int c = (int)(i & 255);
    wbf[i] = __float2bfloat16((c < C) ? wte[n * C + c] : 0.f);
}

// ---------------- lm_head: out[2048][VOC] = A[2048][256] @ B[VOC][256]^T (bf16 MFMA) ----------------
__global__ __launch_bounds__(256) void lmhead_k(const __bf16* __restrict__ A,
                                                const __bf16* __restrict__ Bw,
                                                float* __restrict__ out) {
    int lane = threadIdx.x & 63;
    int wave = threadIdx.x >> 6;
    int wm = wave >> 1, wn = wave & 1;
    int m0 = blockIdx.x * 128 + wm * 64;
    int n0 = blockIdx.y * 128 + wn * 64;
    int r  = lane & 15, q = lane >> 4;
    f32x4 acc[4][4] = {};
    const __bf16* Ap = A + (size_t)(m0 + r) * KPAD + q * 8;
    int brow[4];
#pragma unroll
    for (int nt = 0; nt < 4; ++nt) { int rw = n0 + nt * 16 + r; brow[nt] = (rw < VOC) ? rw : 0; }
    for (int kc = 0; kc < 8; ++kc) {
        int ko = kc * 32;
        bf16x8 a[4], b[4];
#pragma unroll
        for (int mt = 0; mt < 4; ++mt)
            a[mt] = *(const bf16x8*)(Ap + (size_t)mt * 16 * KPAD + ko);
#pragma unroll
        for (int nt = 0; nt < 4; ++nt)
            b[nt] = *(const bf16x8*)(Bw + (size_t)brow[nt] * KPAD + q * 8 + ko);
#pragma unroll
        for (int mt = 0; mt < 4; ++mt)
#pragma unroll
            for (int nt = 0; nt < 4; ++nt)
                acc[mt][nt] = __builtin_amdgcn_mfma_f32_16x16x32_bf16(a[mt], b[nt], acc[mt][nt], 0, 0, 0);
    }
#pragma unroll
    for (int mt = 0; mt < 4; ++mt)
#pragma unroll
        for (int nt = 0; nt < 4; ++nt) {
            int col = n0 + nt * 16 + r;
            if (col < VOC) {
#pragma unroll
                for (int rr = 0; rr < 4; ++rr) {
                    int row = m0 + mt * 16 + q * 4 + rr;
                    out[(size_t)row * VOC + col] = acc[mt][nt][rr];
                }
            }
        }
}

extern "C" void kernel_launch(void* const* d_in, const int* in_sizes, int n_in,
                              void* d_out, int out_size, void* d_ws, size_t ws_size,
                              hipStream_t stream) {
    const int*   idx     = (const int*)d_in[0];
    const float* wte     = (const float*)d_in[1];
    const float* ln1_g   = (const float*)d_in[2];
    const float* ln2_g   = (const float*)d_in[3];
    const float* w_up    = (const float*)d_in[4];
    const float* w_v     = (const float*)d_in[5];
    const float* w_cproj = (const float*)d_in[6];
    const float* w_scan  = (const float*)d_in[7];
    const float* identp  = (const float*)d_in[8];
    const float* w_fc    = (const float*)d_in[9];
    const float* w_proj  = (const float*)d_in[10];
    float* out = (float*)d_out;

    float* ws   = (float*)d_ws;
    float* x    = ws;
    float* buf0 = x    + (size_t)NPOS * C;
    float* buf1 = buf0 + (size_t)NPOS * C;
    float* vbuf = buf1 + (size_t)NPOS * C;
    float* hid  = vbuf + (size_t)NPOS * C;
    float* wuvT = hid  + (size_t)NPOS * HID;
    float* wcT  = wuvT + (size_t)NLAYER * C * 2 * C;
    float* wfcT = wcT  + (size_t)NLAYER * C * C;
    float* wpT  = wfcT + (size_t)NLAYER * C * HID;
    __hip_bfloat16* xbf   = (__hip_bfloat16*)(wpT + (size_t)NLAYER * HID * C);
    __hip_bfloat16* wtebf = xbf + (size_t)NPOS * KPAD;

    dim3 tg1((C * C + 255) / 256, NLAYER);
    transpose_k<<<tg1, 256, 0, stream>>>(w_up,    wuvT, C, C, 2 * C, 0, C * C, C * 2 * C);
    transpose_k<<<tg1, 256, 0, stream>>>(w_v,     wuvT, C, C, 2 * C, C, C * C, C * 2 * C);
    transpose_k<<<tg1, 256, 0, stream>>>(w_cproj, wcT,  C, C, C,     0, C * C, C * C);
    dim3 tg2((HID * C + 255) / 256, NLAYER);
    transpose_k<<<tg2, 256, 0, stream>>>(w_fc,   wfcT, HID, C, HID, 0, HID * C, C * HID);
    transpose_k<<<tg2, 256, 0, stream>>>(w_proj, wpT,  C, HID, C,   0, C * HID, HID * C);

    embed_k<<<NPOS * C / 256, 256, 0, stream>>>(idx, wte, x);

    for (int L = 0; L < NLAYER; ++L) {
        lnuv_k<<<NPOS / 8, 512, 0, stream>>>(x, ln1_g + L * C, wuvT + (size_t)L * C * 2 * C, buf0, vbuf);
        float* cur = buf0; float* oth = buf1;
        for (int off = 1; off < TT; off <<= 1) {
            scan_k<<<NPOS / 8, 512, 0, stream>>>(cur, oth, w_scan + (size_t)L * C * C, identp + L * C, off);
            float* tmp = cur; cur = oth; oth = tmp;
        }
        cproj_k<<<NPOS / 8, 512, 0, stream>>>(cur, vbuf, wcT + (size_t)L * C * C, x);
        lnfc_k<<<NPOS / 8, 512, 0, stream>>>(x, ln2_g + L * C, wfcT + (size_t)L * C * HID, hid);
        proj_k<<<NPOS / 8, 512, 0, stream>>>(hid, wpT + (size_t)L * HID * C, x);
    }

    convx_k<<<NPOS * KPAD / 256, 256, 0, stream>>>(x, xbf);
    convw_k<<<VOC, 256, 0, stream>>>(wte, wtebf);
    lmhead_k<<<dim3(16, 393), 256, 0, stream>>>((const __bf16*)xbf, (const __bf16*)wtebf, out);
}